// Round 1
// baseline (229.937 us; speedup 1.0000x reference)
//
#include <hip/hip_runtime.h>
#include <hip/hip_bf16.h>

typedef __attribute__((ext_vector_type(8))) __bf16 bf16x8;
typedef __attribute__((ext_vector_type(4))) __bf16 bf16x4;
typedef __attribute__((ext_vector_type(4))) float f32x4;

namespace {
constexpr int kB = 8;
constexpr int kT = 2048;
constexpr int kD = 1024;
constexpr int kH = 64;
}

// ---------------------------------------------------------------------------
// Kernel 1: W -> Wt[192][1024] bf16 (transposed, contiguous along K for MFMA
// B-fragments). Softmax scale 1/8 (exact pow2) folded into Wq.
// ---------------------------------------------------------------------------
__global__ __launch_bounds__(256) void wt_kernel(
    const float* __restrict__ Wq, const float* __restrict__ Wk,
    const float* __restrict__ Wv, __bf16* __restrict__ Wt) {
  const int bid = blockIdx.x;  // 0..191 = mat*64 + h
  const int mat = bid >> 6;
  const int h = bid & 63;
  const float* W = (mat == 0) ? Wq : ((mat == 1) ? Wk : Wv);
  const float scale = (mat == 0) ? 0.125f : 1.0f;
  __bf16* dst = Wt + (size_t)bid * kD;
  for (int d = threadIdx.x; d < kD; d += 256)
    dst[d] = (__bf16)(W[(size_t)d * kH + h] * scale);
}

// ---------------------------------------------------------------------------
// Kernel 2: projections. M=16384 rows of x, N=192 (Q|K|V), K=1024.
// Block = 256 threads (4 waves); each wave computes 16 rows x 192 cols.
// Q,K stored row-major [b*T + t][64]; V stored transposed Vt[b][64][t].
// ---------------------------------------------------------------------------
__global__ __launch_bounds__(256) void proj_kernel(
    const float* __restrict__ x, const __bf16* __restrict__ Wt,
    __bf16* __restrict__ Q, __bf16* __restrict__ K, __bf16* __restrict__ Vt) {
  const int wid = threadIdx.x >> 6;
  const int lane = threadIdx.x & 63;
  const int lr = lane & 15;
  const int lg = lane >> 4;
  const int row0 = blockIdx.x * 64 + wid * 16;  // 16-row tile of this wave

  const float* xrow = x + (size_t)(row0 + lr) * kD + lg * 8;

  f32x4 acc[12];
#pragma unroll
  for (int i = 0; i < 12; ++i) acc[i] = (f32x4)(0.0f);

  for (int ks = 0; ks < kD / 32; ++ks) {
    // A fragment: x[row][ks*32 + lg*8 + j], fp32 -> bf16
    const float4* xp = (const float4*)(xrow + ks * 32);
    const float4 x0 = xp[0];
    const float4 x1 = xp[1];
    bf16x8 af;
    af[0] = (__bf16)x0.x; af[1] = (__bf16)x0.y;
    af[2] = (__bf16)x0.z; af[3] = (__bf16)x0.w;
    af[4] = (__bf16)x1.x; af[5] = (__bf16)x1.y;
    af[6] = (__bf16)x1.z; af[7] = (__bf16)x1.w;
#pragma unroll
    for (int nt = 0; nt < 12; ++nt) {
      const bf16x8 bf =
          *(const bf16x8*)(Wt + (size_t)(nt * 16 + lr) * kD + ks * 32 + lg * 8);
      acc[nt] = __builtin_amdgcn_mfma_f32_16x16x32_bf16(af, bf, acc[nt], 0, 0, 0);
    }
  }

  // D layout: col = nt*16 + lr, row = row0 + 4*lg + reg
  const int orow0 = row0 + lg * 4;
#pragma unroll
  for (int nt = 0; nt < 4; ++nt)
#pragma unroll
    for (int r = 0; r < 4; ++r)
      Q[(size_t)(orow0 + r) * kH + nt * 16 + lr] = (__bf16)acc[nt][r];
#pragma unroll
  for (int nt = 4; nt < 8; ++nt)
#pragma unroll
    for (int r = 0; r < 4; ++r)
      K[(size_t)(orow0 + r) * kH + (nt - 4) * 16 + lr] = (__bf16)acc[nt][r];

  const int b = row0 >> 11;          // 2048 rows per batch, tiles never straddle
  const int t0 = (row0 & 2047) + lg * 4;
#pragma unroll
  for (int nt = 8; nt < 12; ++nt) {
    bf16x4 pv;
#pragma unroll
    for (int r = 0; r < 4; ++r) pv[r] = (__bf16)acc[nt][r];
    *(bf16x4*)(Vt + ((size_t)b * kH + (nt - 8) * 16 + lr) * kT + t0) = pv;
  }
}

// ---------------------------------------------------------------------------
// Kernel 3: causal flash attention. Grid (T/64, B), block = 4 waves.
// Wave w owns q-rows [q0, q0+16), q0 = bx*64 + w*16. KV tiles of 32 keys,
// per-wave loop bound (no block barriers). K/Vt read straight from global
// (L2-resident). P transform via per-wave LDS + wave-local lgkmcnt wait.
// ---------------------------------------------------------------------------
__global__ __launch_bounds__(256) void attn_kernel(
    const __bf16* __restrict__ Q, const __bf16* __restrict__ K,
    const __bf16* __restrict__ Vt, float* __restrict__ out) {
  __shared__ alignas(16) __bf16 P_lds[4][16][32];
  const int wid = threadIdx.x >> 6;
  const int lane = threadIdx.x & 63;
  const int lr = lane & 15;
  const int lg = lane >> 4;
  const int b = blockIdx.y;
  const int q0 = blockIdx.x * 64 + wid * 16;

  const __bf16* Qb = Q + (size_t)b * kT * kH;
  const __bf16* Kb = K + (size_t)b * kT * kH;
  const __bf16* Vb = Vt + (size_t)b * kH * kT;

  // Q fragments for this wave's 16 rows (scale already folded into Wq)
  const bf16x8 aq0 = *(const bf16x8*)(Qb + (size_t)(q0 + lr) * kH + lg * 8);
  const bf16x8 aq1 = *(const bf16x8*)(Qb + (size_t)(q0 + lr) * kH + 32 + lg * 8);

  f32x4 o[4];
#pragma unroll
  for (int i = 0; i < 4; ++i) o[i] = (f32x4)(0.0f);
  float m_r[4], l_r[4];
#pragma unroll
  for (int r = 0; r < 4; ++r) { m_r[r] = -1e30f; l_r[r] = 0.0f; }

  const int kv_end = q0 + 16;  // need keys <= q0+15
  for (int kv = 0; kv < kv_end; kv += 32) {
    // ---- S = Q K^T for 16 rows x 32 keys (two 16-key subtiles) ----
    f32x4 s0 = (f32x4)(0.0f), s1 = (f32x4)(0.0f);
    const __bf16* kp = Kb + (size_t)(kv + lr) * kH + lg * 8;
    const bf16x8 bk00 = *(const bf16x8*)(kp);
    const bf16x8 bk01 = *(const bf16x8*)(kp + 32);
    const bf16x8 bk10 = *(const bf16x8*)(kp + (size_t)16 * kH);
    const bf16x8 bk11 = *(const bf16x8*)(kp + (size_t)16 * kH + 32);
    s0 = __builtin_amdgcn_mfma_f32_16x16x32_bf16(aq0, bk00, s0, 0, 0, 0);
    s0 = __builtin_amdgcn_mfma_f32_16x16x32_bf16(aq1, bk01, s0, 0, 0, 0);
    s1 = __builtin_amdgcn_mfma_f32_16x16x32_bf16(aq0, bk10, s1, 0, 0, 0);
    s1 = __builtin_amdgcn_mfma_f32_16x16x32_bf16(aq1, bk11, s1, 0, 0, 0);

    // ---- causal mask (only tiles that touch the diagonal) ----
    if (kv + 31 > q0) {
#pragma unroll
      for (int r = 0; r < 4; ++r) {
        const int rowr = q0 + lg * 4 + r;
        if (kv + lr > rowr) s0[r] = -1e30f;
        if (kv + 16 + lr > rowr) s1[r] = -1e30f;
      }
    }

    // ---- online softmax (row stats live per reg r; cols spread over lr) ----
    float alpha[4];
#pragma unroll
    for (int r = 0; r < 4; ++r) {
      float v = fmaxf(s0[r], s1[r]);
      v = fmaxf(v, __shfl_xor(v, 1, 64));
      v = fmaxf(v, __shfl_xor(v, 2, 64));
      v = fmaxf(v, __shfl_xor(v, 4, 64));
      v = fmaxf(v, __shfl_xor(v, 8, 64));
      const float mn = fmaxf(m_r[r], v);
      alpha[r] = __expf(m_r[r] - mn);
      m_r[r] = mn;
      const float p0 = __expf(s0[r] - mn);
      const float p1 = __expf(s1[r] - mn);
      float sum = p0 + p1;
      sum += __shfl_xor(sum, 1, 64);
      sum += __shfl_xor(sum, 2, 64);
      sum += __shfl_xor(sum, 4, 64);
      sum += __shfl_xor(sum, 8, 64);
      l_r[r] = l_r[r] * alpha[r] + sum;
      // D-layout -> LDS (row-major [16 rows][32 keys])
      P_lds[wid][lg * 4 + r][lr] = (__bf16)p0;
      P_lds[wid][lg * 4 + r][16 + lr] = (__bf16)p1;
#pragma unroll
      for (int ht = 0; ht < 4; ++ht) o[ht][r] *= alpha[r];
    }

    // wave-local: drain ds_writes before the transpose read
    asm volatile("s_waitcnt lgkmcnt(0)" ::: "memory");
    const bf16x8 ap = *(const bf16x8*)(&P_lds[wid][lr][lg * 8]);

    // ---- O += P V  (B operand from Vt, contiguous along keys) ----
#pragma unroll
    for (int ht = 0; ht < 4; ++ht) {
      const bf16x8 bv =
          *(const bf16x8*)(Vb + (size_t)(ht * 16 + lr) * kT + kv + lg * 8);
      o[ht] = __builtin_amdgcn_mfma_f32_16x16x32_bf16(ap, bv, o[ht], 0, 0, 0);
    }
  }

  // ---- epilogue: divide by l, fp32 store ----
  float* ob = out + ((size_t)b * kT + q0 + lg * 4) * kH;
#pragma unroll
  for (int r = 0; r < 4; ++r) {
    const float inv = 1.0f / l_r[r];
#pragma unroll
    for (int ht = 0; ht < 4; ++ht)
      ob[(size_t)r * kH + ht * 16 + lr] = o[ht][r] * inv;
  }
}

// ---------------------------------------------------------------------------
extern "C" void kernel_launch(void* const* d_in, const int* in_sizes, int n_in,
                              void* d_out, int out_size, void* d_ws, size_t ws_size,
                              hipStream_t stream) {
  (void)in_sizes; (void)n_in; (void)out_size; (void)ws_size;
  const float* x  = (const float*)d_in[0];
  const float* Wq = (const float*)d_in[1];
  const float* Wk = (const float*)d_in[2];
  const float* Wv = (const float*)d_in[3];
  float* out = (float*)d_out;

  char* ws = (char*)d_ws;
  // workspace layout (bytes):
  //   Wt : 192*1024*2        = 393216
  //   Q  : 8*2048*64*2       = 2097152
  //   K  : 2097152
  //   Vt : 2097152  (total ~6.4 MB)
  __bf16* Wt = (__bf16*)(ws);
  __bf16* Qp = (__bf16*)(ws + 393216);
  __bf16* Kp = (__bf16*)(ws + 393216 + 2097152);
  __bf16* Vt = (__bf16*)(ws + 393216 + 2 * 2097152);

  wt_kernel<<<192, 256, 0, stream>>>(Wq, Wk, Wv, Wt);
  proj_kernel<<<kB * kT / 64, 256, 0, stream>>>(x, Wt, Qp, Kp, Vt);
  attn_kernel<<<dim3(kT / 64, kB), 256, 0, stream>>>(Qp, Kp, Vt, out);
}

// Round 2
// 211.166 us; speedup vs baseline: 1.0889x; 1.0889x over previous
//
#include <hip/hip_runtime.h>
#include <hip/hip_bf16.h>

typedef __attribute__((ext_vector_type(8))) __bf16 bf16x8;
typedef __attribute__((ext_vector_type(4))) __bf16 bf16x4;
typedef __attribute__((ext_vector_type(4))) float f32x4;

namespace {
constexpr int kB = 8;
constexpr int kT = 2048;
constexpr int kD = 1024;
constexpr int kH = 64;
}

// ---------------------------------------------------------------------------
// Kernel 1: W -> Wt[192][1024] bf16 (transposed, contiguous along K for MFMA
// B-fragments). Softmax scale 1/8 AND log2(e) folded into Wq, so attention
// scores are in exp2 domain (softmax invariant under consistent base change).
// ---------------------------------------------------------------------------
__global__ __launch_bounds__(256) void wt_kernel(
    const float* __restrict__ Wq, const float* __restrict__ Wk,
    const float* __restrict__ Wv, __bf16* __restrict__ Wt) {
  const int bid = blockIdx.x;  // 0..191 = mat*64 + h
  const int mat = bid >> 6;
  const int h = bid & 63;
  const float* W = (mat == 0) ? Wq : ((mat == 1) ? Wk : Wv);
  // 0.125 * log2(e)
  const float scale = (mat == 0) ? 0.18033688011112042f : 1.0f;
  __bf16* dst = Wt + (size_t)bid * kD;
  for (int d = threadIdx.x; d < kD; d += 256)
    dst[d] = (__bf16)(W[(size_t)d * kH + h] * scale);
}

// ---------------------------------------------------------------------------
// Kernel 2: projections. M=16384 rows of x, N=192 (Q|K|V), K=1024.
// Block = 256 threads (4 waves); each wave computes 16 rows x 192 cols.
// Q,K stored row-major [b*T + t][64]; V stored transposed Vt[b][64][t].
// ---------------------------------------------------------------------------
__global__ __launch_bounds__(256) void proj_kernel(
    const float* __restrict__ x, const __bf16* __restrict__ Wt,
    __bf16* __restrict__ Q, __bf16* __restrict__ K, __bf16* __restrict__ Vt) {
  const int wid = threadIdx.x >> 6;
  const int lane = threadIdx.x & 63;
  const int lr = lane & 15;
  const int lg = lane >> 4;
  const int row0 = blockIdx.x * 64 + wid * 16;  // 16-row tile of this wave

  const float* xrow = x + (size_t)(row0 + lr) * kD + lg * 8;

  f32x4 acc[12];
#pragma unroll
  for (int i = 0; i < 12; ++i) acc[i] = (f32x4)(0.0f);

  for (int ks = 0; ks < kD / 32; ++ks) {
    // A fragment: x[row][ks*32 + lg*8 + j], fp32 -> bf16
    const float4* xp = (const float4*)(xrow + ks * 32);
    const float4 x0 = xp[0];
    const float4 x1 = xp[1];
    bf16x8 af;
    af[0] = (__bf16)x0.x; af[1] = (__bf16)x0.y;
    af[2] = (__bf16)x0.z; af[3] = (__bf16)x0.w;
    af[4] = (__bf16)x1.x; af[5] = (__bf16)x1.y;
    af[6] = (__bf16)x1.z; af[7] = (__bf16)x1.w;
#pragma unroll
    for (int nt = 0; nt < 12; ++nt) {
      const bf16x8 bf =
          *(const bf16x8*)(Wt + (size_t)(nt * 16 + lr) * kD + ks * 32 + lg * 8);
      acc[nt] = __builtin_amdgcn_mfma_f32_16x16x32_bf16(af, bf, acc[nt], 0, 0, 0);
    }
  }

  // D layout: col = nt*16 + lr, row = row0 + 4*lg + reg
  const int orow0 = row0 + lg * 4;
#pragma unroll
  for (int nt = 0; nt < 4; ++nt)
#pragma unroll
    for (int r = 0; r < 4; ++r)
      Q[(size_t)(orow0 + r) * kH + nt * 16 + lr] = (__bf16)acc[nt][r];
#pragma unroll
  for (int nt = 4; nt < 8; ++nt)
#pragma unroll
    for (int r = 0; r < 4; ++r)
      K[(size_t)(orow0 + r) * kH + (nt - 4) * 16 + lr] = (__bf16)acc[nt][r];

  const int b = row0 >> 11;          // 2048 rows per batch, tiles never straddle
  const int t0 = (row0 & 2047) + lg * 4;
#pragma unroll
  for (int nt = 8; nt < 12; ++nt) {
    bf16x4 pv;
#pragma unroll
    for (int r = 0; r < 4; ++r) pv[r] = (__bf16)acc[nt][r];
    *(bf16x4*)(Vt + ((size_t)b * kH + (nt - 8) * 16 + lr) * kT + t0) = pv;
  }
}

// ---------------------------------------------------------------------------
// Kernel 3: causal flash attention, swapped-operand (S^T = K Q^T) so softmax
// is in-lane (lane owns q-row = lane&15) and P lands directly in the x32
// B-fragment layout via a permuted K-row assignment -- no LDS in main loop.
// Grid (T/16, B) = 1024 blocks; 4 waves/block split KV tiles mod 4 and merge
// partials (flash-decode style) through a small LDS epilogue.
// ---------------------------------------------------------------------------
__global__ __launch_bounds__(256, 4) void attn_kernel(
    const __bf16* __restrict__ Q, const __bf16* __restrict__ K,
    const __bf16* __restrict__ Vt, float* __restrict__ out) {
  __shared__ alignas(16) float o_s[4][16][68];  // [wave][q][h] pad 64->68
  __shared__ float m_s[4][16], l_s[4][16];

  const int wid = threadIdx.x >> 6;
  const int lane = threadIdx.x & 63;
  const int lr = lane & 15;
  const int lg = lane >> 4;
  const int b = blockIdx.y;
  const int qt = (int)gridDim.x - 1 - (int)blockIdx.x;  // long tiles first
  const int q0 = qt * 16;

  const __bf16* Qb = Q + (size_t)b * kT * kH;
  const __bf16* Kb = K + (size_t)b * kT * kH;
  const __bf16* Vb = Vt + (size_t)b * kH * kT;

  // Q as B-fragment: lane col = q-row = q0+lr, k = d = lg*8+j
  const bf16x8 aq0 = *(const bf16x8*)(Qb + (size_t)(q0 + lr) * kH + lg * 8);
  const bf16x8 aq1 = *(const bf16x8*)(Qb + (size_t)(q0 + lr) * kH + 32 + lg * 8);

  f32x4 o[4];
#pragma unroll
  for (int i = 0; i < 4; ++i) o[i] = (f32x4)(0.0f);
  float m = -1e30f, l = 0.0f;

  const int ntiles = (q0 + 16 + 31) >> 5;  // ceil((q0+16)/32)
  // Permuted K-row for A-operand: subtile-0 rows pick keys 8*(lr/4)+(lr%4),
  // subtile-1 +4 => lane (q,lg) ends holding P for keys 8lg..8lg+7.
  const int krow = 8 * (lr >> 2) + (lr & 3);

  for (int t = wid; t < ntiles; t += 4) {
    const int kv = t * 32;
    const __bf16* kp0 = Kb + (size_t)(kv + krow) * kH + lg * 8;
    const __bf16* kp1 = kp0 + (size_t)4 * kH;  // subtile 1: keys +4

    f32x4 s0 = (f32x4)(0.0f), s1 = (f32x4)(0.0f);
    s0 = __builtin_amdgcn_mfma_f32_16x16x32_bf16(
        *(const bf16x8*)(kp0), aq0, s0, 0, 0, 0);
    s0 = __builtin_amdgcn_mfma_f32_16x16x32_bf16(
        *(const bf16x8*)(kp0 + 32), aq1, s0, 0, 0, 0);
    s1 = __builtin_amdgcn_mfma_f32_16x16x32_bf16(
        *(const bf16x8*)(kp1), aq0, s1, 0, 0, 0);
    s1 = __builtin_amdgcn_mfma_f32_16x16x32_bf16(
        *(const bf16x8*)(kp1 + 32), aq1, s1, 0, 0, 0);

    // causal mask: s0[r] is key kv+8lg+r, s1[r] is key kv+8lg+4+r; q = q0+lr
    if (kv + 31 > q0) {
      const int q = q0 + lr;
#pragma unroll
      for (int r = 0; r < 4; ++r) {
        if (kv + 8 * lg + r > q) s0[r] = -1e30f;
        if (kv + 8 * lg + 4 + r > q) s1[r] = -1e30f;
      }
    }

    // ---- online softmax, exp2 domain, in-lane + 2-lane-group reduce ----
    float pm = fmaxf(fmaxf(fmaxf(s0[0], s0[1]), fmaxf(s0[2], s0[3])),
                     fmaxf(fmaxf(s1[0], s1[1]), fmaxf(s1[2], s1[3])));
    pm = fmaxf(pm, __shfl_xor(pm, 16, 64));
    pm = fmaxf(pm, __shfl_xor(pm, 32, 64));
    const float mn = fmaxf(m, pm);
    const float alpha = exp2f(m - mn);
    m = mn;

    float p0[4], p1[4];
    float sum = 0.0f;
#pragma unroll
    for (int r = 0; r < 4; ++r) {
      p0[r] = exp2f(s0[r] - mn);
      p1[r] = exp2f(s1[r] - mn);
      sum += p0[r] + p1[r];
    }
    sum += __shfl_xor(sum, 16, 64);
    sum += __shfl_xor(sum, 32, 64);
    l = l * alpha + sum;

    bf16x8 pb;
#pragma unroll
    for (int r = 0; r < 4; ++r) {
      pb[r] = (__bf16)p0[r];
      pb[r + 4] = (__bf16)p1[r];
    }

    // ---- O^T += V^T P^T : A = Vt rows (h), B = pb; D col = q = lr ----
#pragma unroll
    for (int ht = 0; ht < 4; ++ht) {
      o[ht] = o[ht] * alpha;
      const bf16x8 va =
          *(const bf16x8*)(Vb + (size_t)(ht * 16 + lr) * kT + kv + lg * 8);
      o[ht] = __builtin_amdgcn_mfma_f32_16x16x32_bf16(va, pb, o[ht], 0, 0, 0);
    }
  }

  // ---- per-wave partials to LDS; lane holds col q=lr, rows h=16ht+4lg+r ----
#pragma unroll
  for (int ht = 0; ht < 4; ++ht)
    *(f32x4*)&o_s[wid][lr][ht * 16 + lg * 4] = o[ht];
  if (lg == 0) {
    m_s[wid][lr] = m;
    l_s[wid][lr] = l;
  }
  __syncthreads();

  // ---- merge 4 wave-partials; thread ti -> (q = ti&15, h-quad = ti>>4) ----
  const int ti = threadIdx.x;
  const int q = ti & 15;
  const int hb = ti >> 4;
  float mm = fmaxf(fmaxf(m_s[0][q], m_s[1][q]), fmaxf(m_s[2][q], m_s[3][q]));
  f32x4 acc = (f32x4)(0.0f);
  float ll = 0.0f;
#pragma unroll
  for (int w = 0; w < 4; ++w) {
    const float sc = exp2f(m_s[w][q] - mm);
    ll += sc * l_s[w][q];
    const f32x4 ov = *(const f32x4*)&o_s[w][q][hb * 4];
    acc += ov * sc;
  }
  const float inv = 1.0f / ll;
  *(f32x4*)(out + ((size_t)b * kT + q0 + q) * kH + hb * 4) = acc * inv;
}

// ---------------------------------------------------------------------------
extern "C" void kernel_launch(void* const* d_in, const int* in_sizes, int n_in,
                              void* d_out, int out_size, void* d_ws, size_t ws_size,
                              hipStream_t stream) {
  (void)in_sizes; (void)n_in; (void)out_size; (void)ws_size;
  const float* x  = (const float*)d_in[0];
  const float* Wq = (const float*)d_in[1];
  const float* Wk = (const float*)d_in[2];
  const float* Wv = (const float*)d_in[3];
  float* out = (float*)d_out;

  char* ws = (char*)d_ws;
  // workspace layout (bytes):
  //   Wt : 192*1024*2        = 393216
  //   Q  : 8*2048*64*2       = 2097152
  //   K  : 2097152
  //   Vt : 2097152  (total ~6.4 MB)
  __bf16* Wt = (__bf16*)(ws);
  __bf16* Qp = (__bf16*)(ws + 393216);
  __bf16* Kp = (__bf16*)(ws + 393216 + 2097152);
  __bf16* Vt = (__bf16*)(ws + 393216 + 2 * 2097152);

  wt_kernel<<<192, 256, 0, stream>>>(Wq, Wk, Wv, Wt);
  proj_kernel<<<kB * kT / 64, 256, 0, stream>>>(x, Wt, Qp, Kp, Vt);
  attn_kernel<<<dim3(kT / 16, kB), 256, 0, stream>>>(Qp, Kp, Vt, out);
}

// Round 3
// 204.489 us; speedup vs baseline: 1.1244x; 1.0327x over previous
//
#include <hip/hip_runtime.h>
#include <hip/hip_bf16.h>

typedef __attribute__((ext_vector_type(8))) __bf16 bf16x8;
typedef __attribute__((ext_vector_type(4))) __bf16 bf16x4;
typedef __attribute__((ext_vector_type(4))) float f32x4;

namespace {
constexpr int kB = 8;
constexpr int kT = 2048;
constexpr int kD = 1024;
constexpr int kH = 64;
}

// ---------------------------------------------------------------------------
// Kernel 1: W -> Wt[192][1024] bf16 (transposed, contiguous along K for MFMA
// B-fragments). Softmax scale 1/8 AND log2(e) folded into Wq, so attention
// scores are in exp2 domain (softmax invariant under consistent base change).
// ---------------------------------------------------------------------------
__global__ __launch_bounds__(256) void wt_kernel(
    const float* __restrict__ Wq, const float* __restrict__ Wk,
    const float* __restrict__ Wv, __bf16* __restrict__ Wt) {
  const int bid = blockIdx.x;  // 0..191 = mat*64 + h
  const int mat = bid >> 6;
  const int h = bid & 63;
  const float* W = (mat == 0) ? Wq : ((mat == 1) ? Wk : Wv);
  // 0.125 * log2(e)
  const float scale = (mat == 0) ? 0.18033688011112042f : 1.0f;
  __bf16* dst = Wt + (size_t)bid * kD;
  for (int d = threadIdx.x; d < kD; d += 256)
    dst[d] = (__bf16)(W[(size_t)d * kH + h] * scale);
}

// ---------------------------------------------------------------------------
// Kernel 2: projections, K-split for occupancy. Grid = M/16 = 1024 blocks,
// 4 waves/block. All 4 waves compute the SAME 16 rows x 192 cols, each over a
// 256-wide K-quarter (8 MFMA steps). Partials reduced via 24KB LDS in two
// phases of 6 N-tiles. 4 blocks/CU -> 4 waves/SIMD (vs 1 before).
// Q,K stored row-major [b*T + t][64]; V stored transposed Vt[b][64][t].
// ---------------------------------------------------------------------------
__global__ __launch_bounds__(256, 4) void proj_kernel(
    const float* __restrict__ x, const __bf16* __restrict__ Wt,
    __bf16* __restrict__ Q, __bf16* __restrict__ K, __bf16* __restrict__ Vt) {
  // [wave w][nt-slot j][lane] f32x4 chunks: 4*6*64*16B = 24 KB
  __shared__ float p_s[4 * 6 * 64 * 4];

  const int wid = threadIdx.x >> 6;  // K-quarter
  const int lane = threadIdx.x & 63;
  const int lr = lane & 15;
  const int lg = lane >> 4;
  const int row0 = blockIdx.x * 16;
  const int kbase = wid * 256;

  const float* xrow = x + (size_t)(row0 + lr) * kD + kbase + lg * 8;
  const __bf16* wrow = Wt + (size_t)lr * kD + kbase + lg * 8;

  f32x4 acc[12];
#pragma unroll
  for (int i = 0; i < 12; ++i) acc[i] = (f32x4)(0.0f);

#pragma unroll 4
  for (int i = 0; i < 8; ++i) {
    // A fragment: x[row0+lr][kbase + i*32 + lg*8 + j], fp32 -> bf16
    const float4 x0 = *(const float4*)(xrow + i * 32);
    const float4 x1 = *(const float4*)(xrow + i * 32 + 4);
    bf16x8 af;
    af[0] = (__bf16)x0.x; af[1] = (__bf16)x0.y;
    af[2] = (__bf16)x0.z; af[3] = (__bf16)x0.w;
    af[4] = (__bf16)x1.x; af[5] = (__bf16)x1.y;
    af[6] = (__bf16)x1.z; af[7] = (__bf16)x1.w;
#pragma unroll
    for (int nt = 0; nt < 12; ++nt) {
      const bf16x8 bf = *(const bf16x8*)(wrow + (size_t)nt * 16 * kD + i * 32);
      acc[nt] = __builtin_amdgcn_mfma_f32_16x16x32_bf16(af, bf, acc[nt], 0, 0, 0);
    }
  }

  // ---- two-phase LDS reduction over the 4 K-quarters ----
  // acc[nt][r] = partial C[row=4lg+r][col=lr] of N-tile nt for K-quarter wid.
  const int ti = threadIdx.x;
  const int col = ti & 15;
  const int rowq = ti >> 4;  // 0..15
  const size_t g = (size_t)row0 + rowq;
  const int b = (int)(g >> 11);
  const int t = (int)(g & 2047);

#pragma unroll
  for (int p = 0; p < 2; ++p) {
    __syncthreads();  // guards reuse of p_s across phases
#pragma unroll
    for (int j = 0; j < 6; ++j)
      *(f32x4*)&p_s[(((wid * 6 + j) << 6) + lane) << 2] = acc[p * 6 + j];
    __syncthreads();
#pragma unroll
    for (int j = 0; j < 6; ++j) {
      const int base = ((((j << 6) + (rowq >> 2) * 16 + col) << 2) | (rowq & 3));
      const float v = p_s[base] + p_s[base + 1536] + p_s[base + 3072] +
                      p_s[base + 4608];
      const int nt = p * 6 + j;
      if (nt < 4) {
        Q[g * kH + nt * 16 + col] = (__bf16)v;
      } else if (nt < 8) {
        K[g * kH + (nt - 4) * 16 + col] = (__bf16)v;
      } else {
        Vt[((size_t)b * kH + (nt - 8) * 16 + col) * kT + t] = (__bf16)v;
      }
    }
  }
}

// ---------------------------------------------------------------------------
// Kernel 3: causal flash attention, swapped-operand (S^T = K Q^T) so softmax
// is in-lane (lane owns q-row = lane&15) and P lands directly in the x32
// B-fragment layout via a permuted K-row assignment -- no LDS in main loop.
// Grid (T/16, B) = 1024 blocks; 4 waves/block split KV tiles mod 4 and merge
// partials (flash-decode style) through a small LDS epilogue.
// ---------------------------------------------------------------------------
__global__ __launch_bounds__(256, 4) void attn_kernel(
    const __bf16* __restrict__ Q, const __bf16* __restrict__ K,
    const __bf16* __restrict__ Vt, float* __restrict__ out) {
  __shared__ alignas(16) float o_s[4][16][68];  // [wave][q][h] pad 64->68
  __shared__ float m_s[4][16], l_s[4][16];

  const int wid = threadIdx.x >> 6;
  const int lane = threadIdx.x & 63;
  const int lr = lane & 15;
  const int lg = lane >> 4;
  const int b = blockIdx.y;
  const int qt = (int)gridDim.x - 1 - (int)blockIdx.x;  // long tiles first
  const int q0 = qt * 16;

  const __bf16* Qb = Q + (size_t)b * kT * kH;
  const __bf16* Kb = K + (size_t)b * kT * kH;
  const __bf16* Vb = Vt + (size_t)b * kH * kT;

  // Q as B-fragment: lane col = q-row = q0+lr, k = d = lg*8+j
  const bf16x8 aq0 = *(const bf16x8*)(Qb + (size_t)(q0 + lr) * kH + lg * 8);
  const bf16x8 aq1 = *(const bf16x8*)(Qb + (size_t)(q0 + lr) * kH + 32 + lg * 8);

  f32x4 o[4];
#pragma unroll
  for (int i = 0; i < 4; ++i) o[i] = (f32x4)(0.0f);
  float m = -1e30f, l = 0.0f;

  const int ntiles = (q0 + 16 + 31) >> 5;  // ceil((q0+16)/32)
  // Permuted K-row for A-operand: subtile-0 rows pick keys 8*(lr/4)+(lr%4),
  // subtile-1 +4 => lane (q,lg) ends holding P for keys 8lg..8lg+7.
  const int krow = 8 * (lr >> 2) + (lr & 3);

  for (int t = wid; t < ntiles; t += 4) {
    const int kv = t * 32;
    const __bf16* kp0 = Kb + (size_t)(kv + krow) * kH + lg * 8;
    const __bf16* kp1 = kp0 + (size_t)4 * kH;  // subtile 1: keys +4

    f32x4 s0 = (f32x4)(0.0f), s1 = (f32x4)(0.0f);
    s0 = __builtin_amdgcn_mfma_f32_16x16x32_bf16(
        *(const bf16x8*)(kp0), aq0, s0, 0, 0, 0);
    s0 = __builtin_amdgcn_mfma_f32_16x16x32_bf16(
        *(const bf16x8*)(kp0 + 32), aq1, s0, 0, 0, 0);
    s1 = __builtin_amdgcn_mfma_f32_16x16x32_bf16(
        *(const bf16x8*)(kp1), aq0, s1, 0, 0, 0);
    s1 = __builtin_amdgcn_mfma_f32_16x16x32_bf16(
        *(const bf16x8*)(kp1 + 32), aq1, s1, 0, 0, 0);

    // causal mask: s0[r] is key kv+8lg+r, s1[r] is key kv+8lg+4+r; q = q0+lr
    if (kv + 31 > q0) {
      const int q = q0 + lr;
#pragma unroll
      for (int r = 0; r < 4; ++r) {
        if (kv + 8 * lg + r > q) s0[r] = -1e30f;
        if (kv + 8 * lg + 4 + r > q) s1[r] = -1e30f;
      }
    }

    // ---- online softmax, exp2 domain, in-lane + 2-lane-group reduce ----
    float pm = fmaxf(fmaxf(fmaxf(s0[0], s0[1]), fmaxf(s0[2], s0[3])),
                     fmaxf(fmaxf(s1[0], s1[1]), fmaxf(s1[2], s1[3])));
    pm = fmaxf(pm, __shfl_xor(pm, 16, 64));
    pm = fmaxf(pm, __shfl_xor(pm, 32, 64));
    const float mn = fmaxf(m, pm);
    const float alpha = exp2f(m - mn);
    m = mn;

    float p0[4], p1[4];
    float sum = 0.0f;
#pragma unroll
    for (int r = 0; r < 4; ++r) {
      p0[r] = exp2f(s0[r] - mn);
      p1[r] = exp2f(s1[r] - mn);
      sum += p0[r] + p1[r];
    }
    sum += __shfl_xor(sum, 16, 64);
    sum += __shfl_xor(sum, 32, 64);
    l = l * alpha + sum;

    bf16x8 pb;
#pragma unroll
    for (int r = 0; r < 4; ++r) {
      pb[r] = (__bf16)p0[r];
      pb[r + 4] = (__bf16)p1[r];
    }

    // ---- O^T += V^T P^T : A = Vt rows (h), B = pb; D col = q = lr ----
#pragma unroll
    for (int ht = 0; ht < 4; ++ht) {
      o[ht] = o[ht] * alpha;
      const bf16x8 va =
          *(const bf16x8*)(Vb + (size_t)(ht * 16 + lr) * kT + kv + lg * 8);
      o[ht] = __builtin_amdgcn_mfma_f32_16x16x32_bf16(va, pb, o[ht], 0, 0, 0);
    }
  }

  // ---- per-wave partials to LDS; lane holds col q=lr, rows h=16ht+4lg+r ----
#pragma unroll
  for (int ht = 0; ht < 4; ++ht)
    *(f32x4*)&o_s[wid][lr][ht * 16 + lg * 4] = o[ht];
  if (lg == 0) {
    m_s[wid][lr] = m;
    l_s[wid][lr] = l;
  }
  __syncthreads();

  // ---- merge 4 wave-partials; thread ti -> (q = ti&15, h-quad = ti>>4) ----
  const int ti = threadIdx.x;
  const int q = ti & 15;
  const int hb = ti >> 4;
  float mm = fmaxf(fmaxf(m_s[0][q], m_s[1][q]), fmaxf(m_s[2][q], m_s[3][q]));
  f32x4 acc = (f32x4)(0.0f);
  float ll = 0.0f;
#pragma unroll
  for (int w = 0; w < 4; ++w) {
    const float sc = exp2f(m_s[w][q] - mm);
    ll += sc * l_s[w][q];
    const f32x4 ov = *(const f32x4*)&o_s[w][q][hb * 4];
    acc += ov * sc;
  }
  const float inv = 1.0f / ll;
  *(f32x4*)(out + ((size_t)b * kT + q0 + q) * kH + hb * 4) = acc * inv;
}

// ---------------------------------------------------------------------------
extern "C" void kernel_launch(void* const* d_in, const int* in_sizes, int n_in,
                              void* d_out, int out_size, void* d_ws, size_t ws_size,
                              hipStream_t stream) {
  (void)in_sizes; (void)n_in; (void)out_size; (void)ws_size;
  const float* x  = (const float*)d_in[0];
  const float* Wq = (const float*)d_in[1];
  const float* Wk = (const float*)d_in[2];
  const float* Wv = (const float*)d_in[3];
  float* out = (float*)d_out;

  char* ws = (char*)d_ws;
  // workspace layout (bytes):
  //   Wt : 192*1024*2        = 393216
  //   Q  : 8*2048*64*2       = 2097152
  //   K  : 2097152
  //   Vt : 2097152  (total ~6.4 MB)
  __bf16* Wt = (__bf16*)(ws);
  __bf16* Qp = (__bf16*)(ws + 393216);
  __bf16* Kp = (__bf16*)(ws + 393216 + 2097152);
  __bf16* Vt = (__bf16*)(ws + 393216 + 2 * 2097152);

  wt_kernel<<<192, 256, 0, stream>>>(Wq, Wk, Wv, Wt);
  proj_kernel<<<kB * kT / 16, 256, 0, stream>>>(x, Wt, Qp, Kp, Vt);
  attn_kernel<<<dim3(kT / 16, kB), 256, 0, stream>>>(Qp, Kp, Vt, out);
}

// Round 4
// 150.455 us; speedup vs baseline: 1.5283x; 1.3591x over previous
//
#include <hip/hip_runtime.h>
#include <hip/hip_bf16.h>

typedef __attribute__((ext_vector_type(8))) __bf16 bf16x8;
typedef __attribute__((ext_vector_type(4))) float f32x4;

namespace {
constexpr int kB = 8;
constexpr int kT = 2048;
constexpr int kD = 1024;
constexpr int kH = 64;
}

// ---------------------------------------------------------------------------
// Kernel 1: W -> wtf fragment layout [nt][ks][lane][8] bf16.
// Chunk (nt,ks): lane (lr,lg) holds Wt[row=nt*16+lr][k=ks*32+lg*8+j], i.e.
// W_mat[k][(nt&3)*16+lr]. One chunk = 1KB, written coalesced.
// Softmax scale 1/8 * log2(e) folded into Wq (exp2-domain softmax).
// ---------------------------------------------------------------------------
__global__ __launch_bounds__(256) void wt_kernel(
    const float* __restrict__ Wq, const float* __restrict__ Wk,
    const float* __restrict__ Wv, __bf16* __restrict__ wtf) {
  const int wid = threadIdx.x >> 6;
  const int lane = threadIdx.x & 63;
  const int lr = lane & 15;
  const int lg = lane >> 4;
  const int p = blockIdx.x * 4 + wid;  // 0..383 = nt*32 + ks
  const int nt = p >> 5;
  const int ks = p & 31;
  const float* W = (nt < 4) ? Wq : ((nt < 8) ? Wk : Wv);
  const float scale = (nt < 4) ? 0.18033688011112042f : 1.0f;
  const int col = (nt & 3) * 16 + lr;
  bf16x8 v;
#pragma unroll
  for (int j = 0; j < 8; ++j)
    v[j] = (__bf16)(W[(size_t)(ks * 32 + lg * 8 + j) * kH + col] * scale);
  *(bf16x8*)(wtf + (size_t)p * 512 + lane * 8) = v;
}

// ---------------------------------------------------------------------------
// Kernel 2: projections. Grid = M/32 = 512 blocks, 4 waves K-split-4.
// Stage: x rows (32 x 1024) -> bf16 -> XOR-swizzled LDS (coalesced reads).
// Loop: A-fragments via ds_read_b128, B-fragments via coalesced wtf loads.
// Reduce 4 K-partials through LDS (aliased with the stage buffer).
// Q,K row-major [t][64]; V in vf fragment layout for attn's PV A-operand.
// ---------------------------------------------------------------------------
__global__ __launch_bounds__(256, 2) void proj_kernel(
    const float* __restrict__ x, const __bf16* __restrict__ wtf,
    __bf16* __restrict__ Q, __bf16* __restrict__ K, __bf16* __restrict__ vf) {
  __shared__ alignas(16) char lds_raw[65536];  // 64KB stage / 48KB reduce alias
  float* p_s = (float*)lds_raw;

  const int tid = threadIdx.x;
  const int wid = tid >> 6;
  const int lane = tid & 63;
  const int lr = lane & 15;
  const int lg = lane >> 4;
  const int row0 = blockIdx.x * 32;

  // ---- stage x: chunk c = row*128 + kc; wave reads 2KB contiguous ----
#pragma unroll
  for (int i = 0; i < 16; ++i) {
    const int c = i * 256 + tid;
    const int row = c >> 7;
    const int kc = c & 127;
    const float* src = x + (size_t)(row0 + row) * kD + kc * 8;
    const float4 a = ((const float4*)src)[0];
    const float4 b = ((const float4*)src)[1];
    bf16x8 v;
    v[0] = (__bf16)a.x; v[1] = (__bf16)a.y; v[2] = (__bf16)a.z; v[3] = (__bf16)a.w;
    v[4] = (__bf16)b.x; v[5] = (__bf16)b.y; v[6] = (__bf16)b.z; v[7] = (__bf16)b.w;
    const int byte = row * 2048 + ((kc * 16) ^ ((row & 7) << 4));
    *(bf16x8*)(lds_raw + byte) = v;
  }
  __syncthreads();

  f32x4 acc[2][12];
#pragma unroll
  for (int a = 0; a < 2; ++a)
#pragma unroll
    for (int nt = 0; nt < 12; ++nt) acc[a][nt] = (f32x4)(0.0f);

  const int swz = (lr & 7) << 4;
#pragma unroll 2
  for (int i = 0; i < 8; ++i) {
    const int kb = (wid * 256 + i * 32 + lg * 8) * 2;
    const bf16x8 a0 = *(const bf16x8*)(lds_raw + lr * 2048 + (kb ^ swz));
    const bf16x8 a1 = *(const bf16x8*)(lds_raw + 32768 + lr * 2048 + (kb ^ swz));
#pragma unroll
    for (int nt = 0; nt < 12; ++nt) {
      const bf16x8 bfrag =
          *(const bf16x8*)(wtf + (size_t)(nt * 32 + wid * 8 + i) * 512 + lane * 8);
      acc[0][nt] = __builtin_amdgcn_mfma_f32_16x16x32_bf16(a0, bfrag, acc[0][nt], 0, 0, 0);
      acc[1][nt] = __builtin_amdgcn_mfma_f32_16x16x32_bf16(a1, bfrag, acc[1][nt], 0, 0, 0);
    }
  }

  // ---- reduce 4 K-quarters; 2 phases (row-tiles), 12 N-tiles each ----
  const int col = tid & 15;
  const int rowq = tid >> 4;
#pragma unroll
  for (int p = 0; p < 2; ++p) {
    __syncthreads();  // stage buffer dead / previous phase done
#pragma unroll
    for (int j = 0; j < 12; ++j)
      *(f32x4*)&p_s[((wid * 12 + j) * 64 + lane) * 4] = acc[p][j];
    __syncthreads();
    const size_t g = (size_t)row0 + p * 16 + rowq;
    const int b = (int)(g >> 11);
    const int t = (int)(g & 2047);
#pragma unroll
    for (int j = 0; j < 12; ++j) {
      const int base = ((j * 64 + (rowq >> 2) * 16 + col) << 2) | (rowq & 3);
      const float v =
          p_s[base] + p_s[base + 3072] + p_s[base + 6144] + p_s[base + 9216];
      if (j < 4) {
        Q[g * kH + j * 16 + col] = (__bf16)v;
      } else if (j < 8) {
        K[g * kH + (j - 4) * 16 + col] = (__bf16)v;
      } else {
        // vf chunk (b, t>>5, ht): slot = ((t&31)>>3)*128 + h_low*8 + (t&7)
        vf[(((size_t)b * 64 + (t >> 5)) * 4 + (j - 8)) * 512 +
           ((t & 31) >> 3) * 128 + col * 8 + (t & 7)] = (__bf16)v;
      }
    }
  }
}

// ---------------------------------------------------------------------------
// Kernel 3: causal flash attention, swapped-operand (S^T = K Q^T) so softmax
// is in-lane (lane owns q-row = lane&15) and P lands directly in the x32
// B-fragment layout via a permuted K-row assignment -- no LDS in main loop.
// V read from vf fragment layout: one coalesced 1KB load per PV A-operand.
// Grid (T/16, B); 4 waves/block split KV tiles mod 4, LDS merge epilogue.
// ---------------------------------------------------------------------------
__global__ __launch_bounds__(256, 4) void attn_kernel(
    const __bf16* __restrict__ Q, const __bf16* __restrict__ K,
    const __bf16* __restrict__ vf, float* __restrict__ out) {
  __shared__ alignas(16) float o_s[4][16][68];
  __shared__ float m_s[4][16], l_s[4][16];

  const int wid = threadIdx.x >> 6;
  const int lane = threadIdx.x & 63;
  const int lr = lane & 15;
  const int lg = lane >> 4;
  const int b = blockIdx.y;
  const int qt = (int)gridDim.x - 1 - (int)blockIdx.x;  // long tiles first
  const int q0 = qt * 16;

  const __bf16* Qb = Q + (size_t)b * kT * kH;
  const __bf16* Kb = K + (size_t)b * kT * kH;
  const __bf16* Vb = vf + (size_t)b * kH * kT;  // b * 131072

  const bf16x8 aq0 = *(const bf16x8*)(Qb + (size_t)(q0 + lr) * kH + lg * 8);
  const bf16x8 aq1 = *(const bf16x8*)(Qb + (size_t)(q0 + lr) * kH + 32 + lg * 8);

  f32x4 o[4];
#pragma unroll
  for (int i = 0; i < 4; ++i) o[i] = (f32x4)(0.0f);
  float m = -1e30f, l = 0.0f;

  const int ntiles = (q0 + 16 + 31) >> 5;
  const int krow = 8 * (lr >> 2) + (lr & 3);

  for (int t = wid; t < ntiles; t += 4) {
    const int kv = t * 32;
    const __bf16* kp0 = Kb + (size_t)(kv + krow) * kH + lg * 8;
    const __bf16* kp1 = kp0 + (size_t)4 * kH;

    f32x4 s0 = (f32x4)(0.0f), s1 = (f32x4)(0.0f);
    s0 = __builtin_amdgcn_mfma_f32_16x16x32_bf16(
        *(const bf16x8*)(kp0), aq0, s0, 0, 0, 0);
    s0 = __builtin_amdgcn_mfma_f32_16x16x32_bf16(
        *(const bf16x8*)(kp0 + 32), aq1, s0, 0, 0, 0);
    s1 = __builtin_amdgcn_mfma_f32_16x16x32_bf16(
        *(const bf16x8*)(kp1), aq0, s1, 0, 0, 0);
    s1 = __builtin_amdgcn_mfma_f32_16x16x32_bf16(
        *(const bf16x8*)(kp1 + 32), aq1, s1, 0, 0, 0);

    if (kv + 31 > q0) {
      const int q = q0 + lr;
#pragma unroll
      for (int r = 0; r < 4; ++r) {
        if (kv + 8 * lg + r > q) s0[r] = -1e30f;
        if (kv + 8 * lg + 4 + r > q) s1[r] = -1e30f;
      }
    }

    float pm = fmaxf(fmaxf(fmaxf(s0[0], s0[1]), fmaxf(s0[2], s0[3])),
                     fmaxf(fmaxf(s1[0], s1[1]), fmaxf(s1[2], s1[3])));
    pm = fmaxf(pm, __shfl_xor(pm, 16, 64));
    pm = fmaxf(pm, __shfl_xor(pm, 32, 64));
    const float mn = fmaxf(m, pm);
    const float alpha = exp2f(m - mn);
    m = mn;

    float p0[4], p1[4];
    float sum = 0.0f;
#pragma unroll
    for (int r = 0; r < 4; ++r) {
      p0[r] = exp2f(s0[r] - mn);
      p1[r] = exp2f(s1[r] - mn);
      sum += p0[r] + p1[r];
    }
    sum += __shfl_xor(sum, 16, 64);
    sum += __shfl_xor(sum, 32, 64);
    l = l * alpha + sum;

    bf16x8 pb;
#pragma unroll
    for (int r = 0; r < 4; ++r) {
      pb[r] = (__bf16)p0[r];
      pb[r + 4] = (__bf16)p1[r];
    }

#pragma unroll
    for (int ht = 0; ht < 4; ++ht) {
      o[ht] = o[ht] * alpha;
      const bf16x8 va =
          *(const bf16x8*)(Vb + ((size_t)(kv >> 5) * 4 + ht) * 512 + lane * 8);
      o[ht] = __builtin_amdgcn_mfma_f32_16x16x32_bf16(va, pb, o[ht], 0, 0, 0);
    }
  }

#pragma unroll
  for (int ht = 0; ht < 4; ++ht)
    *(f32x4*)&o_s[wid][lr][ht * 16 + lg * 4] = o[ht];
  if (lg == 0) {
    m_s[wid][lr] = m;
    l_s[wid][lr] = l;
  }
  __syncthreads();

  const int ti = threadIdx.x;
  const int q = ti & 15;
  const int hb = ti >> 4;
  float mm = fmaxf(fmaxf(m_s[0][q], m_s[1][q]), fmaxf(m_s[2][q], m_s[3][q]));
  f32x4 acc = (f32x4)(0.0f);
  float ll = 0.0f;
#pragma unroll
  for (int w = 0; w < 4; ++w) {
    const float sc = exp2f(m_s[w][q] - mm);
    ll += sc * l_s[w][q];
    const f32x4 ov = *(const f32x4*)&o_s[w][q][hb * 4];
    acc += ov * sc;
  }
  const float inv = 1.0f / ll;
  *(f32x4*)(out + ((size_t)b * kT + q0 + q) * kH + hb * 4) = acc * inv;
}

// ---------------------------------------------------------------------------
extern "C" void kernel_launch(void* const* d_in, const int* in_sizes, int n_in,
                              void* d_out, int out_size, void* d_ws, size_t ws_size,
                              hipStream_t stream) {
  (void)in_sizes; (void)n_in; (void)out_size; (void)ws_size;
  const float* x  = (const float*)d_in[0];
  const float* Wq = (const float*)d_in[1];
  const float* Wk = (const float*)d_in[2];
  const float* Wv = (const float*)d_in[3];
  float* out = (float*)d_out;

  char* ws = (char*)d_ws;
  // workspace layout (bytes):
  //   wtf : 384*512*2 = 393216
  //   Q   : 2097152
  //   K   : 2097152
  //   vf  : 2097152
  __bf16* wtf = (__bf16*)(ws);
  __bf16* Qp  = (__bf16*)(ws + 393216);
  __bf16* Kp  = (__bf16*)(ws + 393216 + 2097152);
  __bf16* vf  = (__bf16*)(ws + 393216 + 2 * 2097152);

  wt_kernel<<<96, 256, 0, stream>>>(Wq, Wk, Wv, wtf);
  proj_kernel<<<kB * kT / 32, 256, 0, stream>>>(x, wtf, Qp, Kp, vf);
  attn_kernel<<<dim3(kT / 16, kB), 256, 0, stream>>>(Qp, Kp, vf, out);
}

// Round 5
// 135.111 us; speedup vs baseline: 1.7018x; 1.1136x over previous
//
#include <hip/hip_runtime.h>
#include <hip/hip_bf16.h>

typedef __attribute__((ext_vector_type(8))) __bf16 bf16x8;
typedef __attribute__((ext_vector_type(4))) float f32x4;

namespace {
constexpr int kB = 8;
constexpr int kT = 2048;
constexpr int kD = 1024;
constexpr int kH = 64;
}

// ---------------------------------------------------------------------------
// Kernel 1: W -> wtf fragment layout [nt][ks][lane][8] bf16.
// Chunk (nt,ks): lane (lr,lg) holds Wt[row=nt*16+lr][k=ks*32+lg*8+j], i.e.
// W_mat[k][(nt&3)*16+lr]. One chunk = 1KB, written coalesced.
// Softmax scale 1/8 * log2(e) folded into Wq (exp2-domain softmax).
// ---------------------------------------------------------------------------
__global__ __launch_bounds__(256) void wt_kernel(
    const float* __restrict__ Wq, const float* __restrict__ Wk,
    const float* __restrict__ Wv, __bf16* __restrict__ wtf) {
  const int wid = threadIdx.x >> 6;
  const int lane = threadIdx.x & 63;
  const int lr = lane & 15;
  const int lg = lane >> 4;
  const int p = blockIdx.x * 4 + wid;  // 0..383 = nt*32 + ks
  const int nt = p >> 5;
  const int ks = p & 31;
  const float* W = (nt < 4) ? Wq : ((nt < 8) ? Wk : Wv);
  const float scale = (nt < 4) ? 0.18033688011112042f : 1.0f;
  const int col = (nt & 3) * 16 + lr;
  bf16x8 v;
#pragma unroll
  for (int j = 0; j < 8; ++j)
    v[j] = (__bf16)(W[(size_t)(ks * 32 + lg * 8 + j) * kH + col] * scale);
  *(bf16x8*)(wtf + (size_t)p * 512 + lane * 8) = v;
}

// ---------------------------------------------------------------------------
// Kernel 2: projections. Grid = M/32 = 512 blocks, 4 waves K-split-4.
// Stage: x rows (32 x 1024) -> bf16 -> XOR-swizzled LDS (coalesced reads).
// Loop: A-fragments via ds_read_b128, B-fragments via coalesced wtf loads.
// Reduce 4 K-partials through LDS (aliased with the stage buffer).
// Q row-major [t][64]; K and V in fragment layouts (kf, vf) so attn's
// per-tile operand loads are single coalesced 1KB reads.
// ---------------------------------------------------------------------------
__global__ __launch_bounds__(256, 2) void proj_kernel(
    const float* __restrict__ x, const __bf16* __restrict__ wtf,
    __bf16* __restrict__ Q, __bf16* __restrict__ kf, __bf16* __restrict__ vf) {
  __shared__ alignas(16) char lds_raw[65536];  // 64KB stage / 48KB reduce alias
  float* p_s = (float*)lds_raw;

  const int tid = threadIdx.x;
  const int wid = tid >> 6;
  const int lane = tid & 63;
  const int lr = lane & 15;
  const int lg = lane >> 4;
  const int row0 = blockIdx.x * 32;

  // ---- stage x: chunk c = row*128 + kc; wave reads 2KB contiguous ----
#pragma unroll
  for (int i = 0; i < 16; ++i) {
    const int c = i * 256 + tid;
    const int row = c >> 7;
    const int kc = c & 127;
    const float* src = x + (size_t)(row0 + row) * kD + kc * 8;
    const float4 a = ((const float4*)src)[0];
    const float4 b = ((const float4*)src)[1];
    bf16x8 v;
    v[0] = (__bf16)a.x; v[1] = (__bf16)a.y; v[2] = (__bf16)a.z; v[3] = (__bf16)a.w;
    v[4] = (__bf16)b.x; v[5] = (__bf16)b.y; v[6] = (__bf16)b.z; v[7] = (__bf16)b.w;
    const int byte = row * 2048 + ((kc * 16) ^ ((row & 7) << 4));
    *(bf16x8*)(lds_raw + byte) = v;
  }
  __syncthreads();

  f32x4 acc[2][12];
#pragma unroll
  for (int a = 0; a < 2; ++a)
#pragma unroll
    for (int nt = 0; nt < 12; ++nt) acc[a][nt] = (f32x4)(0.0f);

  const int swz = (lr & 7) << 4;
#pragma unroll 2
  for (int i = 0; i < 8; ++i) {
    const int kb = (wid * 256 + i * 32 + lg * 8) * 2;
    const bf16x8 a0 = *(const bf16x8*)(lds_raw + lr * 2048 + (kb ^ swz));
    const bf16x8 a1 = *(const bf16x8*)(lds_raw + 32768 + lr * 2048 + (kb ^ swz));
#pragma unroll
    for (int nt = 0; nt < 12; ++nt) {
      const bf16x8 bfrag =
          *(const bf16x8*)(wtf + (size_t)(nt * 32 + wid * 8 + i) * 512 + lane * 8);
      acc[0][nt] = __builtin_amdgcn_mfma_f32_16x16x32_bf16(a0, bfrag, acc[0][nt], 0, 0, 0);
      acc[1][nt] = __builtin_amdgcn_mfma_f32_16x16x32_bf16(a1, bfrag, acc[1][nt], 0, 0, 0);
    }
  }

  // ---- reduce 4 K-quarters; 2 phases (row-tiles), 12 N-tiles each ----
  const int col = tid & 15;
  const int rowq = tid >> 4;
#pragma unroll
  for (int p = 0; p < 2; ++p) {
    __syncthreads();  // stage buffer dead / previous phase done
#pragma unroll
    for (int j = 0; j < 12; ++j)
      *(f32x4*)&p_s[((wid * 12 + j) * 64 + lane) * 4] = acc[p][j];
    __syncthreads();
    const size_t g = (size_t)row0 + p * 16 + rowq;
    const int b = (int)(g >> 11);
    const int t = (int)(g & 2047);
#pragma unroll
    for (int j = 0; j < 12; ++j) {
      const int base = ((j * 64 + (rowq >> 2) * 16 + col) << 2) | (rowq & 3);
      const float v =
          p_s[base] + p_s[base + 3072] + p_s[base + 6144] + p_s[base + 9216];
      if (j < 4) {
        Q[g * kH + j * 16 + col] = (__bf16)v;
      } else if (j < 8) {
        // kf chunk (b, t>>5, c= sub*2 + dhalf): lane l holds
        // K[kv + 8*(lr>>2)+(lr&3) + 4*sub][dhalf*32 + lg*8 + jj]
        const int h = (j - 4) * 16 + col;
        const int r = t & 31;
        const int lrk = ((r >> 3) << 2) | (r & 3);
        const int sub = (r >> 2) & 1;
        const int dh = h >> 5;
        const int lgk = (h & 31) >> 3;
        const int jj = h & 7;
        kf[(((size_t)b * 64 + (t >> 5)) * 4 + sub * 2 + dh) * 512 +
           (lgk * 16 + lrk) * 8 + jj] = (__bf16)v;
      } else {
        // vf chunk (b, t>>5, ht): slot = ((t&31)>>3)*128 + h_low*8 + (t&7)
        vf[(((size_t)b * 64 + (t >> 5)) * 4 + (j - 8)) * 512 +
           ((t & 31) >> 3) * 128 + col * 8 + (t & 7)] = (__bf16)v;
      }
    }
  }
}

// ---------------------------------------------------------------------------
// Kernel 3: causal flash attention, swapped-operand (S^T = K Q^T) so softmax
// is in-lane (lane owns q-row = lane&15) and P lands directly in the x32
// B-fragment layout -- no LDS, no cross-lane in main loop.
// K and V read from fragment layouts (1KB coalesced loads); next tile's
// 8 chunk-loads are issued BEFORE computing the current tile (register
// double-buffer) so load latency hides under MFMA+softmax.
// Grid (T/16, B); 4 waves/block split KV tiles mod 4, LDS merge epilogue.
// ---------------------------------------------------------------------------
__global__ __launch_bounds__(256, 4) void attn_kernel(
    const __bf16* __restrict__ Q, const __bf16* __restrict__ kf,
    const __bf16* __restrict__ vf, float* __restrict__ out) {
  __shared__ alignas(16) float o_s[4][16][68];
  __shared__ float m_s[4][16], l_s[4][16];

  const int wid = threadIdx.x >> 6;
  const int lane = threadIdx.x & 63;
  const int lr = lane & 15;
  const int lg = lane >> 4;
  const int b = blockIdx.y;
  const int qt = (int)gridDim.x - 1 - (int)blockIdx.x;  // long tiles first
  const int q0 = qt * 16;

  const __bf16* Qb = Q + (size_t)b * kT * kH;
  const __bf16* Kf = kf + (size_t)b * 131072 + lane * 8;
  const __bf16* Vf = vf + (size_t)b * 131072 + lane * 8;

  const bf16x8 aq0 = *(const bf16x8*)(Qb + (size_t)(q0 + lr) * kH + lg * 8);
  const bf16x8 aq1 = *(const bf16x8*)(Qb + (size_t)(q0 + lr) * kH + 32 + lg * 8);

  f32x4 o[4];
#pragma unroll
  for (int i = 0; i < 4; ++i) o[i] = (f32x4)(0.0f);
  float m = -1e30f, l = 0.0f;

  const int ntiles = (q0 + 16 + 31) >> 5;

  // ---- preload first tile's K/V chunks ----
  bf16x8 ka[4], va[4];
  {
    const int t0c = (wid < ntiles) ? wid : 0;
#pragma unroll
    for (int c = 0; c < 4; ++c) {
      ka[c] = *(const bf16x8*)(Kf + ((size_t)t0c * 4 + c) * 512);
      va[c] = *(const bf16x8*)(Vf + ((size_t)t0c * 4 + c) * 512);
    }
  }

  for (int t = wid; t < ntiles; t += 4) {
    // ---- issue next tile's loads (land during this tile's compute) ----
    const int tn = (t + 4 < ntiles) ? (t + 4) : t;
    bf16x8 kn[4], vn[4];
#pragma unroll
    for (int c = 0; c < 4; ++c) {
      kn[c] = *(const bf16x8*)(Kf + ((size_t)tn * 4 + c) * 512);
      vn[c] = *(const bf16x8*)(Vf + ((size_t)tn * 4 + c) * 512);
    }

    const int kv = t * 32;
    f32x4 s0 = (f32x4)(0.0f), s1 = (f32x4)(0.0f);
    s0 = __builtin_amdgcn_mfma_f32_16x16x32_bf16(ka[0], aq0, s0, 0, 0, 0);
    s0 = __builtin_amdgcn_mfma_f32_16x16x32_bf16(ka[1], aq1, s0, 0, 0, 0);
    s1 = __builtin_amdgcn_mfma_f32_16x16x32_bf16(ka[2], aq0, s1, 0, 0, 0);
    s1 = __builtin_amdgcn_mfma_f32_16x16x32_bf16(ka[3], aq1, s1, 0, 0, 0);

    // causal mask: s0[r] is key kv+8lg+r, s1[r] is key kv+8lg+4+r; q = q0+lr
    if (kv + 31 > q0) {
      const int q = q0 + lr;
#pragma unroll
      for (int r = 0; r < 4; ++r) {
        if (kv + 8 * lg + r > q) s0[r] = -1e30f;
        if (kv + 8 * lg + 4 + r > q) s1[r] = -1e30f;
      }
    }

    // ---- online softmax, exp2 domain, in-lane + 2-lane-group reduce ----
    float pm = fmaxf(fmaxf(fmaxf(s0[0], s0[1]), fmaxf(s0[2], s0[3])),
                     fmaxf(fmaxf(s1[0], s1[1]), fmaxf(s1[2], s1[3])));
    pm = fmaxf(pm, __shfl_xor(pm, 16, 64));
    pm = fmaxf(pm, __shfl_xor(pm, 32, 64));
    const float mn = fmaxf(m, pm);
    const float alpha = exp2f(m - mn);
    m = mn;

    float p0[4], p1[4];
    float sum = 0.0f;
#pragma unroll
    for (int r = 0; r < 4; ++r) {
      p0[r] = exp2f(s0[r] - mn);
      p1[r] = exp2f(s1[r] - mn);
      sum += p0[r] + p1[r];
    }
    sum += __shfl_xor(sum, 16, 64);
    sum += __shfl_xor(sum, 32, 64);
    l = l * alpha + sum;

    bf16x8 pb;
#pragma unroll
    for (int r = 0; r < 4; ++r) {
      pb[r] = (__bf16)p0[r];
      pb[r + 4] = (__bf16)p1[r];
    }

    // ---- O^T += V^T P^T : A = V chunks (h-rows), B = pb; D col = q = lr ----
#pragma unroll
    for (int ht = 0; ht < 4; ++ht) {
      o[ht] = o[ht] * alpha;
      o[ht] = __builtin_amdgcn_mfma_f32_16x16x32_bf16(va[ht], pb, o[ht], 0, 0, 0);
    }

    // rotate double-buffer (SSA renaming; no real moves after unroll)
#pragma unroll
    for (int c = 0; c < 4; ++c) {
      ka[c] = kn[c];
      va[c] = vn[c];
    }
  }

#pragma unroll
  for (int ht = 0; ht < 4; ++ht)
    *(f32x4*)&o_s[wid][lr][ht * 16 + lg * 4] = o[ht];
  if (lg == 0) {
    m_s[wid][lr] = m;
    l_s[wid][lr] = l;
  }
  __syncthreads();

  const int ti = threadIdx.x;
  const int q = ti & 15;
  const int hb = ti >> 4;
  float mm = fmaxf(fmaxf(m_s[0][q], m_s[1][q]), fmaxf(m_s[2][q], m_s[3][q]));
  f32x4 acc = (f32x4)(0.0f);
  float ll = 0.0f;
#pragma unroll
  for (int w = 0; w < 4; ++w) {
    const float sc = exp2f(m_s[w][q] - mm);
    ll += sc * l_s[w][q];
    const f32x4 ov = *(const f32x4*)&o_s[w][q][hb * 4];
    acc += ov * sc;
  }
  const float inv = 1.0f / ll;
  *(f32x4*)(out + ((size_t)b * kT + q0 + q) * kH + hb * 4) = acc * inv;
}

// ---------------------------------------------------------------------------
extern "C" void kernel_launch(void* const* d_in, const int* in_sizes, int n_in,
                              void* d_out, int out_size, void* d_ws, size_t ws_size,
                              hipStream_t stream) {
  (void)in_sizes; (void)n_in; (void)out_size; (void)ws_size;
  const float* x  = (const float*)d_in[0];
  const float* Wq = (const float*)d_in[1];
  const float* Wk = (const float*)d_in[2];
  const float* Wv = (const float*)d_in[3];
  float* out = (float*)d_out;

  char* ws = (char*)d_ws;
  // workspace layout (bytes):
  //   wtf : 384*512*2 = 393216
  //   Q   : 2097152
  //   kf  : 2097152
  //   vf  : 2097152
  __bf16* wtf = (__bf16*)(ws);
  __bf16* Qp  = (__bf16*)(ws + 393216);
  __bf16* kfp = (__bf16*)(ws + 393216 + 2097152);
  __bf16* vfp = (__bf16*)(ws + 393216 + 2 * 2097152);

  wt_kernel<<<96, 256, 0, stream>>>(Wq, Wk, Wv, wtf);
  proj_kernel<<<kB * kT / 32, 256, 0, stream>>>(x, wtf, Qp, kfp, vfp);
  attn_kernel<<<dim3(kT / 16, kB), 256, 0, stream>>>(Qp, kfp, vfp, out);
}

// Round 8
// 134.255 us; speedup vs baseline: 1.7127x; 1.0064x over previous
//
#include <hip/hip_runtime.h>
#include <hip/hip_bf16.h>

typedef __attribute__((ext_vector_type(8))) __bf16 bf16x8;
typedef __attribute__((ext_vector_type(4))) float f32x4;

namespace {
constexpr int kB = 8;
constexpr int kT = 2048;
constexpr int kD = 1024;
constexpr int kH = 64;
}

// ---------------------------------------------------------------------------
// Kernel 1: W -> wtf fragment layout [nt][ks][lane][8] bf16.
// Chunk (nt,ks): lane (lr,lg) holds Wt[row=nt*16+lr][k=ks*32+lg*8+j], i.e.
// W_mat[k][(nt&3)*16+lr]. One chunk = 1KB, written coalesced.
// Softmax scale 1/8 * log2(e) folded into Wq (exp2-domain softmax).
// ---------------------------------------------------------------------------
__global__ __launch_bounds__(256) void wt_kernel(
    const float* __restrict__ Wq, const float* __restrict__ Wk,
    const float* __restrict__ Wv, __bf16* __restrict__ wtf) {
  const int wid = threadIdx.x >> 6;
  const int lane = threadIdx.x & 63;
  const int lr = lane & 15;
  const int lg = lane >> 4;
  const int p = blockIdx.x * 4 + wid;  // 0..383 = nt*32 + ks
  const int nt = p >> 5;
  const int ks = p & 31;
  const float* W = (nt < 4) ? Wq : ((nt < 8) ? Wk : Wv);
  const float scale = (nt < 4) ? 0.18033688011112042f : 1.0f;
  const int col = (nt & 3) * 16 + lr;
  bf16x8 v;
#pragma unroll
  for (int j = 0; j < 8; ++j)
    v[j] = (__bf16)(W[(size_t)(ks * 32 + lg * 8 + j) * kH + col] * scale);
  *(bf16x8*)(wtf + (size_t)p * 512 + lane * 8) = v;
}

// ---------------------------------------------------------------------------
// Kernel 2: projections (UNCHANGED this round for attribution).
// ---------------------------------------------------------------------------
__global__ __launch_bounds__(256, 2) void proj_kernel(
    const float* __restrict__ x, const __bf16* __restrict__ wtf,
    __bf16* __restrict__ Q, __bf16* __restrict__ kf, __bf16* __restrict__ vf) {
  __shared__ alignas(16) char lds_raw[65536];  // 64KB stage / 48KB reduce alias
  float* p_s = (float*)lds_raw;

  const int tid = threadIdx.x;
  const int wid = tid >> 6;
  const int lane = tid & 63;
  const int lr = lane & 15;
  const int lg = lane >> 4;
  const int row0 = blockIdx.x * 32;

  // ---- stage x: chunk c = row*128 + kc; wave reads 2KB contiguous ----
#pragma unroll
  for (int i = 0; i < 16; ++i) {
    const int c = i * 256 + tid;
    const int row = c >> 7;
    const int kc = c & 127;
    const float* src = x + (size_t)(row0 + row) * kD + kc * 8;
    const float4 a = ((const float4*)src)[0];
    const float4 b = ((const float4*)src)[1];
    bf16x8 v;
    v[0] = (__bf16)a.x; v[1] = (__bf16)a.y; v[2] = (__bf16)a.z; v[3] = (__bf16)a.w;
    v[4] = (__bf16)b.x; v[5] = (__bf16)b.y; v[6] = (__bf16)b.z; v[7] = (__bf16)b.w;
    const int byte = row * 2048 + ((kc * 16) ^ ((row & 7) << 4));
    *(bf16x8*)(lds_raw + byte) = v;
  }
  __syncthreads();

  f32x4 acc[2][12];
#pragma unroll
  for (int a = 0; a < 2; ++a)
#pragma unroll
    for (int nt = 0; nt < 12; ++nt) acc[a][nt] = (f32x4)(0.0f);

  const int swz = (lr & 7) << 4;
#pragma unroll 2
  for (int i = 0; i < 8; ++i) {
    const int kb = (wid * 256 + i * 32 + lg * 8) * 2;
    const bf16x8 a0 = *(const bf16x8*)(lds_raw + lr * 2048 + (kb ^ swz));
    const bf16x8 a1 = *(const bf16x8*)(lds_raw + 32768 + lr * 2048 + (kb ^ swz));
#pragma unroll
    for (int nt = 0; nt < 12; ++nt) {
      const bf16x8 bfrag =
          *(const bf16x8*)(wtf + (size_t)(nt * 32 + wid * 8 + i) * 512 + lane * 8);
      acc[0][nt] = __builtin_amdgcn_mfma_f32_16x16x32_bf16(a0, bfrag, acc[0][nt], 0, 0, 0);
      acc[1][nt] = __builtin_amdgcn_mfma_f32_16x16x32_bf16(a1, bfrag, acc[1][nt], 0, 0, 0);
    }
  }

  // ---- reduce 4 K-quarters; 2 phases (row-tiles), 12 N-tiles each ----
  const int col = tid & 15;
  const int rowq = tid >> 4;
#pragma unroll
  for (int p = 0; p < 2; ++p) {
    __syncthreads();  // stage buffer dead / previous phase done
#pragma unroll
    for (int j = 0; j < 12; ++j)
      *(f32x4*)&p_s[((wid * 12 + j) * 64 + lane) * 4] = acc[p][j];
    __syncthreads();
    const size_t g = (size_t)row0 + p * 16 + rowq;
    const int b = (int)(g >> 11);
    const int t = (int)(g & 2047);
#pragma unroll
    for (int j = 0; j < 12; ++j) {
      const int base = ((j * 64 + (rowq >> 2) * 16 + col) << 2) | (rowq & 3);
      const float v =
          p_s[base] + p_s[base + 3072] + p_s[base + 6144] + p_s[base + 9216];
      if (j < 4) {
        Q[g * kH + j * 16 + col] = (__bf16)v;
      } else if (j < 8) {
        const int h = (j - 4) * 16 + col;
        const int r = t & 31;
        const int lrk = ((r >> 3) << 2) | (r & 3);
        const int sub = (r >> 2) & 1;
        const int dh = h >> 5;
        const int lgk = (h & 31) >> 3;
        const int jj = h & 7;
        kf[(((size_t)b * 64 + (t >> 5)) * 4 + sub * 2 + dh) * 512 +
           (lgk * 16 + lrk) * 8 + jj] = (__bf16)v;
      } else {
        vf[(((size_t)b * 64 + (t >> 5)) * 4 + (j - 8)) * 512 +
           ((t & 31) >> 3) * 128 + col * 8 + (t & 7)] = (__bf16)v;
      }
    }
  }
}

// ---------------------------------------------------------------------------
// Kernel 3: causal flash attention, swapped-operand + register prefetch +
// DEFER-MAX (T13, THR=8 in exp2 domain) and DEFER-L: common-path tile has
// zero cross-lane ops and zero o-rescale. l is a per-lane partial (each lane
// owns 8 keys/tile); lane-group sums merged in the LDS epilogue.
// Grid (T/16, B); 4 waves/block split KV tiles mod 4, LDS merge epilogue.
// ---------------------------------------------------------------------------
__global__ __launch_bounds__(256, 4) void attn_kernel(
    const __bf16* __restrict__ Q, const __bf16* __restrict__ kf,
    const __bf16* __restrict__ vf, float* __restrict__ out) {
  __shared__ alignas(16) float o_s[4][16][68];
  __shared__ float m_s[4][16], l_s[4][4][16];  // [wave][lg][q]

  const int wid = threadIdx.x >> 6;
  const int lane = threadIdx.x & 63;
  const int lr = lane & 15;
  const int lg = lane >> 4;
  const int b = blockIdx.y;
  const int qt = (int)gridDim.x - 1 - (int)blockIdx.x;  // long tiles first
  const int q0 = qt * 16;

  const __bf16* Qb = Q + (size_t)b * kT * kH;
  const __bf16* Kf = kf + (size_t)b * 131072 + lane * 8;
  const __bf16* Vf = vf + (size_t)b * 131072 + lane * 8;

  const bf16x8 aq0 = *(const bf16x8*)(Qb + (size_t)(q0 + lr) * kH + lg * 8);
  const bf16x8 aq1 = *(const bf16x8*)(Qb + (size_t)(q0 + lr) * kH + 32 + lg * 8);

  f32x4 o[4];
#pragma unroll
  for (int i = 0; i < 4; ++i) o[i] = (f32x4)(0.0f);
  float m = -1e30f, l = 0.0f;  // l is a PER-LANE partial (this lane's keys)

  const int ntiles = (q0 + 16 + 31) >> 5;

  // ---- preload first tile's K/V chunks ----
  bf16x8 ka[4], va[4];
  {
    const int t0c = (wid < ntiles) ? wid : 0;
#pragma unroll
    for (int c = 0; c < 4; ++c) {
      ka[c] = *(const bf16x8*)(Kf + ((size_t)t0c * 4 + c) * 512);
      va[c] = *(const bf16x8*)(Vf + ((size_t)t0c * 4 + c) * 512);
    }
  }

  for (int t = wid; t < ntiles; t += 4) {
    // ---- issue next tile's loads (land during this tile's compute) ----
    const int tn = (t + 4 < ntiles) ? (t + 4) : t;
    bf16x8 kn[4], vn[4];
#pragma unroll
    for (int c = 0; c < 4; ++c) {
      kn[c] = *(const bf16x8*)(Kf + ((size_t)tn * 4 + c) * 512);
      vn[c] = *(const bf16x8*)(Vf + ((size_t)tn * 4 + c) * 512);
    }

    const int kv = t * 32;
    f32x4 s0 = (f32x4)(0.0f), s1 = (f32x4)(0.0f);
    s0 = __builtin_amdgcn_mfma_f32_16x16x32_bf16(ka[0], aq0, s0, 0, 0, 0);
    s0 = __builtin_amdgcn_mfma_f32_16x16x32_bf16(ka[1], aq1, s0, 0, 0, 0);
    s1 = __builtin_amdgcn_mfma_f32_16x16x32_bf16(ka[2], aq0, s1, 0, 0, 0);
    s1 = __builtin_amdgcn_mfma_f32_16x16x32_bf16(ka[3], aq1, s1, 0, 0, 0);

    // causal mask: s0[r] is key kv+8lg+r, s1[r] is key kv+8lg+4+r; q = q0+lr
    if (kv + 31 > q0) {
      const int q = q0 + lr;
#pragma unroll
      for (int r = 0; r < 4; ++r) {
        if (kv + 8 * lg + r > q) s0[r] = -1e30f;
        if (kv + 8 * lg + 4 + r > q) s1[r] = -1e30f;
      }
    }

    // ---- defer-max online softmax (exp2 domain) ----
    const float pm = fmaxf(fmaxf(fmaxf(s0[0], s0[1]), fmaxf(s0[2], s0[3])),
                           fmaxf(fmaxf(s1[0], s1[1]), fmaxf(s1[2], s1[3])));
    if (!__all(pm - m <= 8.0f)) {
      // rare path: cross-lane max over the 4 lane-groups sharing q=lr
      float t2 = fmaxf(pm, __shfl_xor(pm, 16, 64));
      t2 = fmaxf(t2, __shfl_xor(t2, 32, 64));
      const float mn = fmaxf(m, t2);
      const float alpha = exp2f(m - mn);
#pragma unroll
      for (int ht = 0; ht < 4; ++ht) o[ht] = o[ht] * alpha;
      l *= alpha;
      m = mn;
    }

    float sum = 0.0f;
    bf16x8 pb;
#pragma unroll
    for (int r = 0; r < 4; ++r) {
      const float p0 = exp2f(s0[r] - m);
      const float p1 = exp2f(s1[r] - m);
      sum += p0 + p1;
      pb[r] = (__bf16)p0;
      pb[r + 4] = (__bf16)p1;
    }
    l += sum;

    // ---- O^T += V^T P^T : A = V chunks (h-rows), B = pb; D col = q = lr ----
#pragma unroll
    for (int ht = 0; ht < 4; ++ht)
      o[ht] = __builtin_amdgcn_mfma_f32_16x16x32_bf16(va[ht], pb, o[ht], 0, 0, 0);

    // rotate double-buffer (SSA renaming; no real moves after unroll)
#pragma unroll
    for (int c = 0; c < 4; ++c) {
      ka[c] = kn[c];
      va[c] = vn[c];
    }
  }

#pragma unroll
  for (int ht = 0; ht < 4; ++ht)
    *(f32x4*)&o_s[wid][lr][ht * 16 + lg * 4] = o[ht];
  if (lg == 0) m_s[wid][lr] = m;  // m uniform across lane-groups
  l_s[wid][lg][lr] = l;           // per-lane-group partial sums
  __syncthreads();

  // ---- merge 4 wave-partials; thread ti -> (q = ti&15, h-quad = ti>>4) ----
  const int ti = threadIdx.x;
  const int q = ti & 15;
  const int hb = ti >> 4;
  float mm = fmaxf(fmaxf(m_s[0][q], m_s[1][q]), fmaxf(m_s[2][q], m_s[3][q]));
  f32x4 acc = (f32x4)(0.0f);
  float ll = 0.0f;
#pragma unroll
  for (int w = 0; w < 4; ++w) {
    const float sc = exp2f(m_s[w][q] - mm);
    const float lw =
        l_s[w][0][q] + l_s[w][1][q] + l_s[w][2][q] + l_s[w][3][q];
    ll += sc * lw;
    const f32x4 ov = *(const f32x4*)&o_s[w][q][hb * 4];
    acc += ov * sc;
  }
  const float inv = 1.0f / ll;
  *(f32x4*)(out + ((size_t)b * kT + q0 + q) * kH + hb * 4) = acc * inv;
}

// ---------------------------------------------------------------------------
extern "C" void kernel_launch(void* const* d_in, const int* in_sizes, int n_in,
                              void* d_out, int out_size, void* d_ws, size_t ws_size,
                              hipStream_t stream) {
  (void)in_sizes; (void)n_in; (void)out_size; (void)ws_size;
  const float* x  = (const float*)d_in[0];
  const float* Wq = (const float*)d_in[1];
  const float* Wk = (const float*)d_in[2];
  const float* Wv = (const float*)d_in[3];
  float* out = (float*)d_out;

  char* ws = (char*)d_ws;
  // workspace layout (bytes):
  //   wtf : 384*512*2 = 393216
  //   Q   : 2097152
  //   kf  : 2097152
  //   vf  : 2097152
  __bf16* wtf = (__bf16*)(ws);
  __bf16* Qp  = (__bf16*)(ws + 393216);
  __bf16* kfp = (__bf16*)(ws + 393216 + 2097152);
  __bf16* vfp = (__bf16*)(ws + 393216 + 2 * 2097152);

  wt_kernel<<<96, 256, 0, stream>>>(Wq, Wk, Wv, wtf);
  proj_kernel<<<kB * kT / 32, 256, 0, stream>>>(x, wtf, Qp, kfp, vfp);
  attn_kernel<<<dim3(kT / 16, kB), 256, 0, stream>>>(Qp, kfp, vfp, out);
}